// Round 5
// baseline (272.620 us; speedup 1.0000x reference)
//
#include <hip/hip_runtime.h>

typedef unsigned short ushort_t;
typedef unsigned int uint32;
typedef __bf16 bf16x8 __attribute__((ext_vector_type(8)));
typedef float f32x4 __attribute__((ext_vector_type(4)));

#define NB 4
#define NH 16
#define NS 4096
#define ND 64
#define NBH 64
#define EPSF 1e-6f

#define CH1 16
#define ROWS1 (NS / CH1)          // 256 rows per pass1 block
#define P2R 64                    // pass2 rows per block (1 strip of 16 per wave)
#define LDJ 70                    // pass1 ushort row stride (word stride 35)
#define LDJW 35
#define BTSZ (80 * 64)            // ushorts per B-panel per bh

__device__ __forceinline__ float phi_f(float x) {
    // elu(x)+1 : x>0 ? x+1 : exp(x)
    return x > 0.0f ? x + 1.0f : __expf(x);
}
__device__ __forceinline__ ushort_t bf16_rn(float x) {
    uint32 u = __float_as_uint(x);
    uint32 r = (u + 0x7FFFu + ((u >> 16) & 1u)) >> 16;
    return (ushort_t)r;
}
__device__ __forceinline__ void split2(float x, ushort_t& h, ushort_t& l) {
    h = bf16_rn(x);
    float hf = __uint_as_float(((uint32)h) << 16);
    l = bf16_rn(x - hf);
}
union FragU { uint32 u[4]; bf16x8 v; };
__device__ __forceinline__ bf16x8 ld_frag(const ushort_t* arr, int widx) {
    const uint32* p = (const uint32*)arr;
    FragU f;
    f.u[0] = p[widx]; f.u[1] = p[widx + 1]; f.u[2] = p[widx + 2]; f.u[3] = p[widx + 3];
    return f.v;
}
union FragP { ushort_t s[8]; bf16x8 v; };
__device__ __forceinline__ f32x4 mfma16(bf16x8 a, bf16x8 b, f32x4 c) {
    return __builtin_amdgcn_mfma_f32_16x16x32_bf16(a, b, c, 0, 0, 0);
}

// =====================================================================
// Pass 1: partial KV = phiK^T @ V over a 256-row chunk (+ partial k1).
// Coalesced global loads (round 4). NEW this round: the 4-tile loop is
// FULLY UNROLLED with explicit two-set register double-buffering and a
// sched_barrier(0) pin after each 12-load batch, so the compiler cannot
// sink/serialize the loads (round-4 VGPR_Count=32 proved it did).
// Target: ~12 loads in flight per wave -> deep MLP.
// =====================================================================
template<bool PART>
__global__ __launch_bounds__(256, 4)
void la_pass1(const float* __restrict__ Kin, const float* __restrict__ Vin,
              const float* __restrict__ Min, float* __restrict__ okv,
              float* __restrict__ ok1)
{
    const int t  = threadIdx.x;
    const int cx = blockIdx.x;
    const int bh = blockIdx.y;
    const int bb = bh >> 4;                   // H = 16
    const float* Kb = Kin + (long long)bh * NS * ND;
    const float* Vb = Vin + (long long)bh * NS * ND;
    const float* Mb = Min + (long long)bb * NS;

    __shared__ __align__(16) ushort_t skh[64 * LDJ], skl[64 * LDJ];
    __shared__ __align__(16) ushort_t svh[64 * LDJ], svl[64 * LDJ];

    const int rr0 = t >> 4;                   // base row within tile (0..15)
    const int c   = (t & 15) * 4;             // col base (d)
    const int wv  = t >> 6;                   // wave id 0..3 -> d-strip 16*wv
    const int m   = t & 15;
    const int q   = (t & 63) >> 4;

    const f32x4 zf = {0.f, 0.f, 0.f, 0.f};
    f32x4 acc0 = zf, acc1 = zf, acc2 = zf, acc3 = zf;
    float k1loc[4] = {0.f, 0.f, 0.f, 0.f};

    const int s0 = cx * ROWS1;

    float4 kR[2][4], vR[2][4];
    float  mR[2][4];
#define LOADT(tt, sset) { \
        const long long rb_ = (long long)(s0 + (tt) * 64 + rr0); \
        const float* kp_ = Kb + rb_ * ND + c; \
        const float* vp_ = Vb + rb_ * ND + c; \
        kR[sset][0] = *(const float4*)(kp_);            vR[sset][0] = *(const float4*)(vp_); \
        kR[sset][1] = *(const float4*)(kp_ + 16 * ND);  vR[sset][1] = *(const float4*)(vp_ + 16 * ND); \
        kR[sset][2] = *(const float4*)(kp_ + 32 * ND);  vR[sset][2] = *(const float4*)(vp_ + 32 * ND); \
        kR[sset][3] = *(const float4*)(kp_ + 48 * ND);  vR[sset][3] = *(const float4*)(vp_ + 48 * ND); \
        mR[sset][0] = Mb[rb_];      mR[sset][1] = Mb[rb_ + 16]; \
        mR[sset][2] = Mb[rb_ + 32]; mR[sset][3] = Mb[rb_ + 48]; }

    LOADT(0, 0);
    __builtin_amdgcn_sched_barrier(0);        // pin the batch: no sinking

    #pragma unroll
    for (int tile = 0; tile < ROWS1 / 64; ++tile) {
        const int cur = tile & 1;
        const int nxt = cur ^ 1;
        if (tile + 1 < ROWS1 / 64) {
            LOADT(tile + 1, nxt);             // batch-issue next tile's 12 loads
            __builtin_amdgcn_sched_barrier(0); // pin: issue before any compute
        }
        __syncthreads();                       // previous tile's MFMA reads done
        #pragma unroll
        for (int j = 0; j < 4; ++j) {
            const int rr = rr0 + 16 * j;       // s within tile
            const float xs[4] = {kR[cur][j].x, kR[cur][j].y, kR[cur][j].z, kR[cur][j].w};
            const float vs[4] = {vR[cur][j].x, vR[cur][j].y, vR[cur][j].z, vR[cur][j].w};
            const float mj = mR[cur][j];
            #pragma unroll
            for (int i = 0; i < 4; ++i) {
                const float x = phi_f(xs[i]) * mj;
                k1loc[i] += x;
                ushort_t h, l;
                split2(x, h, l);
                skh[(c + i) * LDJ + rr] = h;
                skl[(c + i) * LDJ + rr] = l;
                split2(vs[i], h, l);
                svh[(c + i) * LDJ + rr] = h;
                svl[(c + i) * LDJ + rr] = l;
            }
        }
        __syncthreads();
        #pragma unroll
        for (int ks = 0; ks < 2; ++ks) {
            const int fo = ks * 16 + q * 4;
            const bf16x8 ah = ld_frag(skh, (16 * wv + m) * LDJW + fo);
            const bf16x8 al = ld_frag(skl, (16 * wv + m) * LDJW + fo);
            {
                const bf16x8 fbh = ld_frag(svh, (0 + m) * LDJW + fo);
                const bf16x8 fbl = ld_frag(svl, (0 + m) * LDJW + fo);
                acc0 = mfma16(al, fbh, acc0); acc0 = mfma16(ah, fbl, acc0); acc0 = mfma16(ah, fbh, acc0);
            }
            {
                const bf16x8 fbh = ld_frag(svh, (16 + m) * LDJW + fo);
                const bf16x8 fbl = ld_frag(svl, (16 + m) * LDJW + fo);
                acc1 = mfma16(al, fbh, acc1); acc1 = mfma16(ah, fbl, acc1); acc1 = mfma16(ah, fbh, acc1);
            }
            {
                const bf16x8 fbh = ld_frag(svh, (32 + m) * LDJW + fo);
                const bf16x8 fbl = ld_frag(svl, (32 + m) * LDJW + fo);
                acc2 = mfma16(al, fbh, acc2); acc2 = mfma16(ah, fbl, acc2); acc2 = mfma16(ah, fbh, acc2);
            }
            {
                const bf16x8 fbh = ld_frag(svh, (48 + m) * LDJW + fo);
                const bf16x8 fbl = ld_frag(svl, (48 + m) * LDJW + fo);
                acc3 = mfma16(al, fbh, acc3); acc3 = mfma16(ah, fbl, acc3); acc3 = mfma16(ah, fbh, acc3);
            }
        }
    }
#undef LOADT

    // ---- store partial KV (D[row=q*4+i within strip][col=16nt+m]) ----
    const int dbase = 16 * wv + q * 4;
    if (PART) {
        float* outp = okv + (long long)(bh * CH1 + cx) * (ND * ND);
        #pragma unroll
        for (int i = 0; i < 4; ++i) {
            outp[(dbase + i) * ND +  0 + m] = acc0[i];
            outp[(dbase + i) * ND + 16 + m] = acc1[i];
            outp[(dbase + i) * ND + 32 + m] = acc2[i];
            outp[(dbase + i) * ND + 48 + m] = acc3[i];
        }
    } else {
        float* outp = okv + (long long)bh * (ND * ND);
        #pragma unroll
        for (int i = 0; i < 4; ++i) {
            atomicAdd(&outp[(dbase + i) * ND +  0 + m], acc0[i]);
            atomicAdd(&outp[(dbase + i) * ND + 16 + m], acc1[i]);
            atomicAdd(&outp[(dbase + i) * ND + 32 + m], acc2[i]);
            atomicAdd(&outp[(dbase + i) * ND + 48 + m], acc3[i]);
        }
    }
    // ---- k1 partial reduce through LDS ----
    __syncthreads();
    float* red = (float*)skh;                  // 64*17 floats = 4352 B <= 8960 B
    #pragma unroll
    for (int i = 0; i < 4; ++i) red[(c + i) * 17 + rr0] = k1loc[i];
    __syncthreads();
    if (t < 64) {
        float s = 0.f;
        #pragma unroll
        for (int g = 0; g < 16; ++g) s += red[t * 17 + g];
        if (PART) ok1[(bh * CH1 + cx) * ND + t] = s;
        else      atomicAdd(&ok1[bh * ND + t], s);
    }
}

// =====================================================================
// Reduce: sum CH1 partial KV tiles + k1 partials, emit the pass-2 B
// panel directly as split bf16 hi/lo, TRANSPOSED ([n=v][k=d], 80 rows:
// row 64 = k1, rows 65..79 = 0). Pass 2 fragment-loads it from global.
// =====================================================================
__global__ __launch_bounds__(256)
void la_reduce(const float* __restrict__ pkv, const float* __restrict__ pk1,
               ushort_t* __restrict__ BTh, ushort_t* __restrict__ BTl)
{
    const int t = threadIdx.x;
    const int bh = blockIdx.x;
    const float4* src = (const float4*)(pkv + (long long)bh * CH1 * ND * ND);
    float4 a[4];
    #pragma unroll
    for (int i = 0; i < 4; ++i) { a[i].x = 0.f; a[i].y = 0.f; a[i].z = 0.f; a[i].w = 0.f; }
    for (int c = 0; c < CH1; ++c) {
        #pragma unroll
        for (int i = 0; i < 4; ++i) {
            const float4 v = src[c * 1024 + t + 256 * i];
            a[i].x += v.x; a[i].y += v.y; a[i].z += v.z; a[i].w += v.w;
        }
    }
    ushort_t* oh = BTh + (long long)bh * BTSZ;
    ushort_t* ol = BTl + (long long)bh * BTSZ;
    #pragma unroll
    for (int i = 0; i < 4; ++i) {
        const int e4 = t + 256 * i;            // float4 index within 64x64 tile
        const int d  = e4 >> 4;                // row of KV
        const int v0 = (e4 & 15) * 4;          // col of KV
        const float vals[4] = {a[i].x, a[i].y, a[i].z, a[i].w};
        #pragma unroll
        for (int j = 0; j < 4; ++j) {
            ushort_t h, l; split2(vals[j], h, l);
            oh[(v0 + j) * ND + d] = h;         // transposed: BT[v][d]
            ol[(v0 + j) * ND + d] = l;
        }
    }
    if (t < ND) {
        float s = 0.f;
        for (int c = 0; c < CH1; ++c) s += pk1[(bh * CH1 + c) * ND + t];
        ushort_t h, l; split2(s, h, l);
        oh[64 * ND + t] = h; ol[64 * ND + t] = l;
    }
    for (int z = t; z < 15 * 64; z += 256) { oh[65 * ND + z] = 0; ol[65 * ND + z] = 0; }
}

// Fallback-path converter (atomic-accumulated fp32 KV/k1 -> BT panels)
__global__ __launch_bounds__(256)
void la_convert(const float* __restrict__ kv, const float* __restrict__ k1,
                ushort_t* __restrict__ BTh, ushort_t* __restrict__ BTl)
{
    const int t = threadIdx.x;
    const int bh = blockIdx.x;
    const float* kvb = kv + (long long)bh * ND * ND;
    ushort_t* oh = BTh + (long long)bh * BTSZ;
    ushort_t* ol = BTl + (long long)bh * BTSZ;
    for (int e = t; e < ND * ND; e += 256) {
        const int d = e >> 6, v = e & 63;
        ushort_t h, l; split2(kvb[e], h, l);
        oh[v * ND + d] = h; ol[v * ND + d] = l;
    }
    if (t < ND) { ushort_t h, l; split2(k1[bh * ND + t], h, l); oh[64 * ND + t] = h; ol[64 * ND + t] = l; }
    for (int z = t; z < 15 * 64; z += 256) { oh[65 * ND + z] = 0; ol[65 * ND + z] = 0; }
}

// =====================================================================
// Pass 2: out = (phiQ @ [KV | k1]) / norm, split-fp32 MFMA.
// LDS-free, barrier-free. NEW this round: ALL 24 global loads (4 Q +
// 20 B fragments) batch-issued into named registers up-front, then
// sched_barrier(0), then convert + MFMA. launch_bounds(256,2) gives
// the register allocator room (~150 VGPR) so the batch survives.
// Deep per-wave MLP replaces occupancy as the latency-hiding mechanism.
// =====================================================================
__global__ __launch_bounds__(256, 2)
void la_pass2(const float* __restrict__ Qin, const ushort_t* __restrict__ BTh,
              const ushort_t* __restrict__ BTl, float* __restrict__ Out)
{
    const int t  = threadIdx.x;
    const int bh = blockIdx.y;
    const int s0 = blockIdx.x * P2R;
    const long long base = (long long)bh * NS * ND;
    const int wv = t >> 6;
    const int m  = t & 15;
    const int q  = (t & 63) >> 4;
    const int lane = t & 63;
    const ushort_t* Bh = BTh + (long long)bh * BTSZ;
    const ushort_t* Bl = BTl + (long long)bh * BTSZ;

    // ---- batch-issue ALL loads: 4 Q float4s, then 20 B fragments ----
    const int row = s0 + 16 * wv + m;
    const float* qp = Qin + base + (long long)row * ND;
    float4 qv[4];
    qv[0] = *(const float4*)(qp + q * 8);
    qv[1] = *(const float4*)(qp + q * 8 + 4);
    qv[2] = *(const float4*)(qp + 32 + q * 8);
    qv[3] = *(const float4*)(qp + 32 + q * 8 + 4);
    bf16x8 fbh[5][2], fbl[5][2];
    #pragma unroll
    for (int nt = 0; nt < 5; ++nt) {
        #pragma unroll
        for (int ks = 0; ks < 2; ++ks) {
            const int bo = (16 * nt + m) * ND + ks * 32 + q * 8;   // 16B aligned
            fbh[nt][ks] = *(const bf16x8*)(Bh + bo);
            fbl[nt][ks] = *(const bf16x8*)(Bl + bo);
        }
    }
    __builtin_amdgcn_sched_barrier(0);         // pin: all 24 loads issued first

    // ---- convert Q -> A fragments (overlaps B loads still in flight) ----
    bf16x8 aH[2], aL[2];
    #pragma unroll
    for (int ks = 0; ks < 2; ++ks) {
        const float xs[8] = {qv[2 * ks].x, qv[2 * ks].y, qv[2 * ks].z, qv[2 * ks].w,
                             qv[2 * ks + 1].x, qv[2 * ks + 1].y, qv[2 * ks + 1].z, qv[2 * ks + 1].w};
        FragP fh, fl;
        #pragma unroll
        for (int i = 0; i < 8; ++i) {
            ushort_t h, l; split2(phi_f(xs[i] * 0.125f), h, l);
            fh.s[i] = h; fl.s[i] = l;
        }
        aH[ks] = fh.v; aL[ks] = fl.v;
    }

    const f32x4 zf = {0.f, 0.f, 0.f, 0.f};
    f32x4 acc[5];
    #pragma unroll
    for (int b = 0; b < 5; ++b) acc[b] = zf;

    #pragma unroll
    for (int nt = 0; nt < 5; ++nt) {
        #pragma unroll
        for (int ks = 0; ks < 2; ++ks) {
            acc[nt] = mfma16(aL[ks], fbh[nt][ks], acc[nt]);
            acc[nt] = mfma16(aH[ks], fbl[nt][ks], acc[nt]);
            acc[nt] = mfma16(aH[ks], fbh[nt][ks], acc[nt]);
        }
    }

    // ---- epilogue: normalizer in acc[4] col 0 (lane m==0) ----
    float* outb = Out + base;
    const int rbase = s0 + 16 * wv + q * 4;
    #pragma unroll
    for (int i = 0; i < 4; ++i) {
        const float nv = __shfl(acc[4][i], lane & 48, 64);
        const float rn = 1.0f / (nv + EPSF);
        const long long ro = (long long)(rbase + i) * ND;
        outb[ro +  0 + m] = acc[0][i] * rn;
        outb[ro + 16 + m] = acc[1][i] * rn;
        outb[ro + 32 + m] = acc[2][i] * rn;
        outb[ro + 48 + m] = acc[3][i] * rn;
    }
}

extern "C" void kernel_launch(void* const* d_in, const int* in_sizes, int n_in,
                              void* d_out, int out_size, void* d_ws, size_t ws_size,
                              hipStream_t stream)
{
    const float* Q = (const float*)d_in[0];
    const float* K = (const float*)d_in[1];
    const float* V = (const float*)d_in[2];
    const float* M = (const float*)d_in[3];
    float* Out = (float*)d_out;

    const size_t partf = (size_t)NBH * CH1 * ND * ND;   // 4,194,304 floats
    const size_t pk1f  = (size_t)NBH * CH1 * ND;        //    65,536
    const size_t kvf   = (size_t)NBH * ND * ND;         //   262,144
    const size_t k1f   = (size_t)NBH * ND;              //     4,096
    const size_t btu   = (size_t)NBH * BTSZ;            //   327,680 ushorts per panel
    const size_t need  = (partf + pk1f) * sizeof(float) + 2 * btu * sizeof(ushort_t); // ~18.4 MB

    if (ws_size >= need) {
        float* PKV = (float*)d_ws;
        float* PK1 = PKV + partf;
        ushort_t* BThp = (ushort_t*)(PK1 + pk1f);
        ushort_t* BTlp = BThp + btu;
        la_pass1<true><<<dim3(CH1, NBH), dim3(256), 0, stream>>>(K, V, M, PKV, PK1);
        la_reduce<<<dim3(NBH), dim3(256), 0, stream>>>(PKV, PK1, BThp, BTlp);
        la_pass2<<<dim3(NS / P2R, NBH), dim3(256), 0, stream>>>(Q, BThp, BTlp, Out);
    } else {
        float* KVb = (float*)d_ws;
        float* K1b = KVb + kvf;
        ushort_t* BThp = (ushort_t*)(K1b + k1f);
        ushort_t* BTlp = BThp + btu;
        hipMemsetAsync(d_ws, 0, (kvf + k1f) * sizeof(float), stream);
        la_pass1<false><<<dim3(CH1, NBH), dim3(256), 0, stream>>>(K, V, M, KVb, K1b);
        la_convert<<<dim3(NBH), dim3(256), 0, stream>>>(KVb, K1b, BThp, BTlp);
        la_pass2<<<dim3(NS / P2R, NBH), dim3(256), 0, stream>>>(Q, BThp, BTlp, Out);
    }
}

// Round 6
// 248.814 us; speedup vs baseline: 1.0957x; 1.0957x over previous
//
#include <hip/hip_runtime.h>

typedef unsigned short ushort_t;
typedef unsigned int uint32;
typedef __bf16 bf16x8 __attribute__((ext_vector_type(8)));
typedef float f32x4 __attribute__((ext_vector_type(4)));

#define NB 4
#define NH 16
#define NS 4096
#define ND 64
#define NBH 64
#define EPSF 1e-6f

#define CH1 8
#define ROWS1 (NS / CH1)          // 512 rows per pass1 block
#define NT1 (ROWS1 / 64)          // 8 tiles
#define LDJ 70                    // pass1 ushort row stride (word stride 35)
#define LDJW 35
#define BTSZ (80 * 64)            // ushorts per B-panel per bh

__device__ __forceinline__ float phi_f(float x) {
    // elu(x)+1 : x>0 ? x+1 : exp(x)
    return x > 0.0f ? x + 1.0f : __expf(x);
}
__device__ __forceinline__ ushort_t bf16_rn(float x) {
    uint32 u = __float_as_uint(x);
    uint32 r = (u + 0x7FFFu + ((u >> 16) & 1u)) >> 16;
    return (ushort_t)r;
}
__device__ __forceinline__ void split2(float x, ushort_t& h, ushort_t& l) {
    h = bf16_rn(x);
    float hf = __uint_as_float(((uint32)h) << 16);
    l = bf16_rn(x - hf);
}
union FragU { uint32 u[4]; bf16x8 v; };
__device__ __forceinline__ bf16x8 ld_frag(const ushort_t* arr, int widx) {
    const uint32* p = (const uint32*)arr;
    FragU f;
    f.u[0] = p[widx]; f.u[1] = p[widx + 1]; f.u[2] = p[widx + 2]; f.u[3] = p[widx + 3];
    return f.v;
}
union FragP { ushort_t s[8]; bf16x8 v; };
__device__ __forceinline__ f32x4 mfma16(bf16x8 a, bf16x8 b, f32x4 c) {
    return __builtin_amdgcn_mfma_f32_16x16x32_bf16(a, b, c, 0, 0, 0);
}

// =====================================================================
// Pass 1: partial KV = phiK^T @ V over a 512-row chunk (+ partial k1).
// Coalesced global loads; LDS transpose (round-4 body, verified).
// NEW: next tile's 12 loads are issued immediately AFTER the LDS-ready
// barrier, BEFORE the MFMA phase — the only placement in a 2-barrier
// loop where the issue->next-barrier distance is the whole MFMA phase.
// (__syncthreads compiles to s_waitcnt vmcnt(0); any loads in flight at
// a barrier are drained — rounds 0/1/5 issued right before a barrier
// and ate full HBM latency per tile.) No sched_barrier pins (m141).
// CH1=8: 8 tiles/block amortizes the one-time prologue stall.
// =====================================================================
template<bool PART>
__global__ __launch_bounds__(256, 4)
void la_pass1(const float* __restrict__ Kin, const float* __restrict__ Vin,
              const float* __restrict__ Min, float* __restrict__ okv,
              float* __restrict__ ok1)
{
    const int t  = threadIdx.x;
    const int cx = blockIdx.x;
    const int bh = blockIdx.y;
    const int bb = bh >> 4;                   // H = 16
    const float* Kb = Kin + (long long)bh * NS * ND;
    const float* Vb = Vin + (long long)bh * NS * ND;
    const float* Mb = Min + (long long)bb * NS;

    __shared__ __align__(16) ushort_t skh[64 * LDJ], skl[64 * LDJ];
    __shared__ __align__(16) ushort_t svh[64 * LDJ], svl[64 * LDJ];

    const int rr0 = t >> 4;                   // base row within tile (0..15)
    const int c   = (t & 15) * 4;             // col base (d)
    const int wv  = t >> 6;                   // wave id 0..3 -> d-strip 16*wv
    const int m   = t & 15;
    const int q   = (t & 63) >> 4;

    const f32x4 zf = {0.f, 0.f, 0.f, 0.f};
    f32x4 acc0 = zf, acc1 = zf, acc2 = zf, acc3 = zf;
    float k1loc[4] = {0.f, 0.f, 0.f, 0.f};

    const int s0 = cx * ROWS1;

    float4 kR[2][4], vR[2][4];
    float  mR[2][4];
#define LOADT(tt, ss) { \
        const long long rb_ = (long long)(s0 + (tt) * 64 + rr0); \
        const float* kp_ = Kb + rb_ * ND + c; \
        const float* vp_ = Vb + rb_ * ND + c; \
        kR[ss][0] = *(const float4*)(kp_);            vR[ss][0] = *(const float4*)(vp_); \
        kR[ss][1] = *(const float4*)(kp_ + 16 * ND);  vR[ss][1] = *(const float4*)(vp_ + 16 * ND); \
        kR[ss][2] = *(const float4*)(kp_ + 32 * ND);  vR[ss][2] = *(const float4*)(vp_ + 32 * ND); \
        kR[ss][3] = *(const float4*)(kp_ + 48 * ND);  vR[ss][3] = *(const float4*)(vp_ + 48 * ND); \
        mR[ss][0] = Mb[rb_];      mR[ss][1] = Mb[rb_ + 16]; \
        mR[ss][2] = Mb[rb_ + 32]; mR[ss][3] = Mb[rb_ + 48]; }

    LOADT(0, 0);

    #pragma unroll
    for (int tile = 0; tile < NT1; ++tile) {
        const int cur = tile & 1;              // static under full unroll
        __syncthreads();                       // LDS free (prev MFMA done); drains prev set
        // ---- convert current set -> LDS (use-wait on cur loads lands here) ----
        #pragma unroll
        for (int j = 0; j < 4; ++j) {
            const int rr = rr0 + 16 * j;       // s within tile
            const float xs[4] = {kR[cur][j].x, kR[cur][j].y, kR[cur][j].z, kR[cur][j].w};
            const float vs[4] = {vR[cur][j].x, vR[cur][j].y, vR[cur][j].z, vR[cur][j].w};
            const float mj = mR[cur][j];
            #pragma unroll
            for (int i = 0; i < 4; ++i) {
                const float x = phi_f(xs[i]) * mj;
                k1loc[i] += x;
                ushort_t h, l;
                split2(x, h, l);
                skh[(c + i) * LDJ + rr] = h;
                skl[(c + i) * LDJ + rr] = l;
                split2(vs[i], h, l);
                svh[(c + i) * LDJ + rr] = h;
                svl[(c + i) * LDJ + rr] = l;
            }
        }
        __syncthreads();                       // LDS ready
        if (tile + 1 < NT1) {
            LOADT(tile + 1, cur ^ 1);          // issue HERE: covered by whole MFMA phase
        }
        // ---- MFMA phase (ds_read + 24 MFMA ~500cy: hides load latency) ----
        #pragma unroll
        for (int ks = 0; ks < 2; ++ks) {
            const int fo = ks * 16 + q * 4;
            const bf16x8 ah = ld_frag(skh, (16 * wv + m) * LDJW + fo);
            const bf16x8 al = ld_frag(skl, (16 * wv + m) * LDJW + fo);
            {
                const bf16x8 fbh = ld_frag(svh, (0 + m) * LDJW + fo);
                const bf16x8 fbl = ld_frag(svl, (0 + m) * LDJW + fo);
                acc0 = mfma16(al, fbh, acc0); acc0 = mfma16(ah, fbl, acc0); acc0 = mfma16(ah, fbh, acc0);
            }
            {
                const bf16x8 fbh = ld_frag(svh, (16 + m) * LDJW + fo);
                const bf16x8 fbl = ld_frag(svl, (16 + m) * LDJW + fo);
                acc1 = mfma16(al, fbh, acc1); acc1 = mfma16(ah, fbl, acc1); acc1 = mfma16(ah, fbh, acc1);
            }
            {
                const bf16x8 fbh = ld_frag(svh, (32 + m) * LDJW + fo);
                const bf16x8 fbl = ld_frag(svl, (32 + m) * LDJW + fo);
                acc2 = mfma16(al, fbh, acc2); acc2 = mfma16(ah, fbl, acc2); acc2 = mfma16(ah, fbh, acc2);
            }
            {
                const bf16x8 fbh = ld_frag(svh, (48 + m) * LDJW + fo);
                const bf16x8 fbl = ld_frag(svl, (48 + m) * LDJW + fo);
                acc3 = mfma16(al, fbh, acc3); acc3 = mfma16(ah, fbl, acc3); acc3 = mfma16(ah, fbh, acc3);
            }
        }
    }
#undef LOADT

    // ---- store partial KV (D[row=q*4+i within strip][col=16nt+m]) ----
    const int dbase = 16 * wv + q * 4;
    if (PART) {
        float* outp = okv + (long long)(bh * CH1 + cx) * (ND * ND);
        #pragma unroll
        for (int i = 0; i < 4; ++i) {
            outp[(dbase + i) * ND +  0 + m] = acc0[i];
            outp[(dbase + i) * ND + 16 + m] = acc1[i];
            outp[(dbase + i) * ND + 32 + m] = acc2[i];
            outp[(dbase + i) * ND + 48 + m] = acc3[i];
        }
    } else {
        float* outp = okv + (long long)bh * (ND * ND);
        #pragma unroll
        for (int i = 0; i < 4; ++i) {
            atomicAdd(&outp[(dbase + i) * ND +  0 + m], acc0[i]);
            atomicAdd(&outp[(dbase + i) * ND + 16 + m], acc1[i]);
            atomicAdd(&outp[(dbase + i) * ND + 32 + m], acc2[i]);
            atomicAdd(&outp[(dbase + i) * ND + 48 + m], acc3[i]);
        }
    }
    // ---- k1 partial reduce through LDS ----
    __syncthreads();
    float* red = (float*)skh;                  // 64*17 floats = 4352 B <= 8960 B
    #pragma unroll
    for (int i = 0; i < 4; ++i) red[(c + i) * 17 + rr0] = k1loc[i];
    __syncthreads();
    if (t < 64) {
        float s = 0.f;
        #pragma unroll
        for (int g = 0; g < 16; ++g) s += red[t * 17 + g];
        if (PART) ok1[(bh * CH1 + cx) * ND + t] = s;
        else      atomicAdd(&ok1[bh * ND + t], s);
    }
}

// =====================================================================
// Reduce: sum CH1 partial KV tiles + k1 partials, emit the pass-2 B
// panel directly as split bf16 hi/lo, TRANSPOSED ([n=v][k=d], 80 rows:
// row 64 = k1, rows 65..79 = 0). Pass 2 fragment-loads it from global.
// =====================================================================
__global__ __launch_bounds__(256)
void la_reduce(const float* __restrict__ pkv, const float* __restrict__ pk1,
               ushort_t* __restrict__ BTh, ushort_t* __restrict__ BTl)
{
    const int t = threadIdx.x;
    const int bh = blockIdx.x;
    const float4* src = (const float4*)(pkv + (long long)bh * CH1 * ND * ND);
    float4 a[4];
    #pragma unroll
    for (int i = 0; i < 4; ++i) { a[i].x = 0.f; a[i].y = 0.f; a[i].z = 0.f; a[i].w = 0.f; }
    for (int c = 0; c < CH1; ++c) {
        #pragma unroll
        for (int i = 0; i < 4; ++i) {
            const float4 v = src[c * 1024 + t + 256 * i];
            a[i].x += v.x; a[i].y += v.y; a[i].z += v.z; a[i].w += v.w;
        }
    }
    ushort_t* oh = BTh + (long long)bh * BTSZ;
    ushort_t* ol = BTl + (long long)bh * BTSZ;
    #pragma unroll
    for (int i = 0; i < 4; ++i) {
        const int e4 = t + 256 * i;            // float4 index within 64x64 tile
        const int d  = e4 >> 4;                // row of KV
        const int v0 = (e4 & 15) * 4;          // col of KV
        const float vals[4] = {a[i].x, a[i].y, a[i].z, a[i].w};
        #pragma unroll
        for (int j = 0; j < 4; ++j) {
            ushort_t h, l; split2(vals[j], h, l);
            oh[(v0 + j) * ND + d] = h;         // transposed: BT[v][d]
            ol[(v0 + j) * ND + d] = l;
        }
    }
    if (t < ND) {
        float s = 0.f;
        for (int c = 0; c < CH1; ++c) s += pk1[(bh * CH1 + c) * ND + t];
        ushort_t h, l; split2(s, h, l);
        oh[64 * ND + t] = h; ol[64 * ND + t] = l;
    }
    for (int z = t; z < 15 * 64; z += 256) { oh[65 * ND + z] = 0; ol[65 * ND + z] = 0; }
}

// Fallback-path converter (atomic-accumulated fp32 KV/k1 -> BT panels)
__global__ __launch_bounds__(256)
void la_convert(const float* __restrict__ kv, const float* __restrict__ k1,
                ushort_t* __restrict__ BTh, ushort_t* __restrict__ BTl)
{
    const int t = threadIdx.x;
    const int bh = blockIdx.x;
    const float* kvb = kv + (long long)bh * ND * ND;
    ushort_t* oh = BTh + (long long)bh * BTSZ;
    ushort_t* ol = BTl + (long long)bh * BTSZ;
    for (int e = t; e < ND * ND; e += 256) {
        const int d = e >> 6, v = e & 63;
        ushort_t h, l; split2(kvb[e], h, l);
        oh[v * ND + d] = h; ol[v * ND + d] = l;
    }
    if (t < ND) { ushort_t h, l; split2(k1[bh * ND + t], h, l); oh[64 * ND + t] = h; ol[64 * ND + t] = l; }
    for (int z = t; z < 15 * 64; z += 256) { oh[65 * ND + z] = 0; ol[65 * ND + z] = 0; }
}

// =====================================================================
// Pass 2 helpers: Q strip load + full strip body (convert+MFMA+store).
// =====================================================================
__device__ __forceinline__ void p2_load(const float* __restrict__ qp, float4* qs, int q)
{
    qs[0] = *(const float4*)(qp + q * 8);
    qs[1] = *(const float4*)(qp + q * 8 + 4);
    qs[2] = *(const float4*)(qp + 32 + q * 8);
    qs[3] = *(const float4*)(qp + 32 + q * 8 + 4);
}

__device__ __forceinline__ void p2_body(const float4* qs, int rbase, int m, int q, int lane,
                                        const bf16x8 (&fbh)[5][2], const bf16x8 (&fbl)[5][2],
                                        float* __restrict__ outb)
{
    bf16x8 aH[2], aL[2];
    #pragma unroll
    for (int ks = 0; ks < 2; ++ks) {
        const float xs[8] = {qs[2 * ks].x, qs[2 * ks].y, qs[2 * ks].z, qs[2 * ks].w,
                             qs[2 * ks + 1].x, qs[2 * ks + 1].y, qs[2 * ks + 1].z, qs[2 * ks + 1].w};
        FragP fh, fl;
        #pragma unroll
        for (int i = 0; i < 8; ++i) {
            ushort_t h, l; split2(phi_f(xs[i] * 0.125f), h, l);
            fh.s[i] = h; fl.s[i] = l;
        }
        aH[ks] = fh.v; aL[ks] = fl.v;
    }
    const f32x4 zf = {0.f, 0.f, 0.f, 0.f};
    f32x4 acc[5];
    #pragma unroll
    for (int b = 0; b < 5; ++b) acc[b] = zf;
    #pragma unroll
    for (int nt = 0; nt < 5; ++nt) {
        #pragma unroll
        for (int ks = 0; ks < 2; ++ks) {
            acc[nt] = mfma16(aL[ks], fbh[nt][ks], acc[nt]);
            acc[nt] = mfma16(aH[ks], fbl[nt][ks], acc[nt]);
            acc[nt] = mfma16(aH[ks], fbh[nt][ks], acc[nt]);
        }
    }
    #pragma unroll
    for (int i = 0; i < 4; ++i) {
        const float nv = __shfl(acc[4][i], lane & 48, 64);
        const float rn = 1.0f / (nv + EPSF);
        const long long ro = (long long)(rbase + i) * ND;
        outb[ro +  0 + m] = acc[0][i] * rn;
        outb[ro + 16 + m] = acc[1][i] * rn;
        outb[ro + 32 + m] = acc[2][i] * rn;
        outb[ro + 48 + m] = acc[3][i] * rn;
    }
}

// =====================================================================
// Pass 2: out = (phiQ @ [KV | k1]) / norm, split-fp32 MFMA.
// NEW: B panel (20 KB, L2-resident) loaded ONCE into registers per
// wave, reused across 4 Q-strips. Barrier-free software pipeline over
// strips (LQ0,LQ1,B0,LQ2,B1,LQ3,B2,B3): no barriers -> no vmcnt drains;
// each strip's Q loads stay in flight under the previous strip's body.
// launch_bounds(256,2) so the ~150-VGPR working set isn't squeezed to
// 32 VGPR (round-4 failure: compiler sank loads, ~2 in flight).
// =====================================================================
__global__ __launch_bounds__(256, 2)
void la_pass2(const float* __restrict__ Qin, const ushort_t* __restrict__ BTh,
              const ushort_t* __restrict__ BTl, float* __restrict__ Out)
{
    const int t  = threadIdx.x;
    const int bh = blockIdx.y;
    const int s0 = blockIdx.x * 256;          // 256 rows per block (4 strips/wave)
    const long long base = (long long)bh * NS * ND;
    const int wv = t >> 6;
    const int m  = t & 15;
    const int q  = (t & 63) >> 4;
    const int lane = t & 63;
    const ushort_t* Bh = BTh + (long long)bh * BTSZ;
    const ushort_t* Bl = BTl + (long long)bh * BTSZ;
    float* outb = Out + base;

    // ---- B fragments: load once, keep in registers for all strips ----
    bf16x8 fbh[5][2], fbl[5][2];
    #pragma unroll
    for (int nt = 0; nt < 5; ++nt) {
        #pragma unroll
        for (int ks = 0; ks < 2; ++ks) {
            const int bo = (16 * nt + m) * ND + ks * 32 + q * 8;   // 16B aligned
            fbh[nt][ks] = *(const bf16x8*)(Bh + bo);
            fbl[nt][ks] = *(const bf16x8*)(Bl + bo);
        }
    }

    // strip it -> rows s0 + (it*4+wv)*16 + [0,16)
    const float* qp0 = Qin + base + (long long)(s0 + (0 * 4 + wv) * 16 + m) * ND;
    const float* qp1 = Qin + base + (long long)(s0 + (1 * 4 + wv) * 16 + m) * ND;
    const float* qp2 = Qin + base + (long long)(s0 + (2 * 4 + wv) * 16 + m) * ND;
    const float* qp3 = Qin + base + (long long)(s0 + (3 * 4 + wv) * 16 + m) * ND;
    const int rb0 = s0 + (0 * 4 + wv) * 16 + q * 4;
    const int rb1 = s0 + (1 * 4 + wv) * 16 + q * 4;
    const int rb2 = s0 + (2 * 4 + wv) * 16 + q * 4;
    const int rb3 = s0 + (3 * 4 + wv) * 16 + q * 4;

    float4 qA[4], qB[4];
    p2_load(qp0, qA, q);
    p2_load(qp1, qB, q);
    p2_body(qA, rb0, m, q, lane, fbh, fbl, outb);
    p2_load(qp2, qA, q);
    p2_body(qB, rb1, m, q, lane, fbh, fbl, outb);
    p2_load(qp3, qB, q);
    p2_body(qA, rb2, m, q, lane, fbh, fbl, outb);
    p2_body(qB, rb3, m, q, lane, fbh, fbl, outb);
}

extern "C" void kernel_launch(void* const* d_in, const int* in_sizes, int n_in,
                              void* d_out, int out_size, void* d_ws, size_t ws_size,
                              hipStream_t stream)
{
    const float* Q = (const float*)d_in[0];
    const float* K = (const float*)d_in[1];
    const float* V = (const float*)d_in[2];
    const float* M = (const float*)d_in[3];
    float* Out = (float*)d_out;

    const size_t partf = (size_t)NBH * CH1 * ND * ND;   // 2,097,152 floats
    const size_t pk1f  = (size_t)NBH * CH1 * ND;        //    32,768
    const size_t kvf   = (size_t)NBH * ND * ND;         //   262,144
    const size_t k1f   = (size_t)NBH * ND;              //     4,096
    const size_t btu   = (size_t)NBH * BTSZ;            //   327,680 ushorts per panel
    const size_t need  = (partf + pk1f) * sizeof(float) + 2 * btu * sizeof(ushort_t); // ~9.8 MB

    if (ws_size >= need) {
        float* PKV = (float*)d_ws;
        float* PK1 = PKV + partf;
        ushort_t* BThp = (ushort_t*)(PK1 + pk1f);
        ushort_t* BTlp = BThp + btu;
        la_pass1<true><<<dim3(CH1, NBH), dim3(256), 0, stream>>>(K, V, M, PKV, PK1);
        la_reduce<<<dim3(NBH), dim3(256), 0, stream>>>(PKV, PK1, BThp, BTlp);
        la_pass2<<<dim3(NS / 256, NBH), dim3(256), 0, stream>>>(Q, BThp, BTlp, Out);
    } else {
        float* KVb = (float*)d_ws;
        float* K1b = KVb + kvf;
        ushort_t* BThp = (ushort_t*)(K1b + k1f);
        ushort_t* BTlp = BThp + btu;
        hipMemsetAsync(d_ws, 0, (kvf + k1f) * sizeof(float), stream);
        la_pass1<false><<<dim3(CH1, NBH), dim3(256), 0, stream>>>(K, V, M, KVb, K1b);
        la_convert<<<dim3(NBH), dim3(256), 0, stream>>>(KVb, K1b, BThp, BTlp);
        la_pass2<<<dim3(NS / 256, NBH), dim3(256), 0, stream>>>(Q, BThp, BTlp, Out);
    }
}